// Round 8
// baseline (193.569 us; speedup 1.0000x reference)
//
#include <hip/hip_runtime.h>
#include <hip/hip_bf16.h>

// B=4, T=4096, C=1024, H=64 causal attention w/ RPE bias.
// Round 17: R16 (QBLK32) proved latency-bound invariance: half the traffic,
// half the steps, half the waves -> identical 43us. VGPR=84 showed the K/V
// register double-buffer was SUNK by the scheduler for the 3rd time (needs
// ~145 live). Single mechanism this round: __builtin_amdgcn_sched_barrier(0)
// between next-step load issue and current-step compute — loads cannot sink
// past the fence, buffers stay live, steady-state waits become counted vmcnt
// with a full COMPUTEK of cover. Everything else identical to R16.

#define T_DIM 4096
#define C_DIM 1024
#define CK    256          // flash key-chunk (keys per po partial)

typedef __attribute__((ext_vector_type(8))) short s16x8;
typedef __attribute__((ext_vector_type(4))) float f32x4;
typedef __attribute__((ext_vector_type(2))) unsigned int u32x2;
typedef __attribute__((ext_vector_type(4))) unsigned int u32x4;

__device__ __forceinline__ short f2bf(float f) {
    unsigned u = __builtin_bit_cast(unsigned, f);
    u += 0x7FFFu + ((u >> 16) & 1u);
    return (short)(u >> 16);
}
__device__ __forceinline__ unsigned pack2(float a, float b) {
    unsigned ua = __builtin_bit_cast(unsigned, a);
    unsigned ub = __builtin_bit_cast(unsigned, b);
    ua += 0x7FFFu + ((ua >> 16) & 1u);
    ub += 0x7FFFu + ((ub >> 16) & 1u);
    return __builtin_amdgcn_perm(ub, ua, 0x07060302u);
}
__device__ __forceinline__ float bf2f(short s) {
    unsigned u = ((unsigned)(unsigned short)s) << 16;
    return __builtin_bit_cast(float, u);
}
// prefix of active 256-key chunks before 16-q-strip qt: nchunks(j)=j/16+1
__device__ __forceinline__ int chunk_off(int qt) {
    int g = qt >> 4, r = qt & 15;
    return qt + 8 * g * (g - 1) + r * g;
}

// ---------------------------------------------------------------------------
// Kernel 1: weights -> B-fragment order: wfrag[ksAll][mat][nt][lane][8] bf16.
// w_q scaled by 0.125. grid (32, 3) x 256.
// ---------------------------------------------------------------------------
__global__ __launch_bounds__(256) void prep_frag(
    const float* __restrict__ wk, const float* __restrict__ wq,
    const float* __restrict__ wv, short* __restrict__ wfrag)
{
    int ksAll = blockIdx.x, mat = blockIdx.y;
    const float* w = (mat == 0) ? wk : ((mat == 1) ? wq : wv);
    float sc = (mat == 1) ? 0.125f : 1.0f;
    int nt = threadIdx.x >> 6, lane = threadIdx.x & 63;
    int quad = lane >> 4, l15 = lane & 15;
    int h = nt * 16 + l15;
    int cb = ksAll * 32 + quad * 8;
    s16x8 v;
    #pragma unroll
    for (int j = 0; j < 8; ++j) v[j] = f2bf(w[(cb + j) * 64 + h] * sc);
    *(s16x8*)&wfrag[((ksAll * 12 + mat * 4 + nt) * 64 + lane) * 8] = v;
}

// ---------------------------------------------------------------------------
// Kernel 2: fused projection, 32 rows/block, x staged coalesced into LDS,
// wfrag B-fragments double-buffered in registers (L2-latency hiding).
// grid 512 x 256 (4 waves = 2 row-tiles x 2 C-halves).
// ---------------------------------------------------------------------------
union ProjSmem {
    short xs[32][1032];                 // staged x rows (bf16); 1032 pad -> 2-way banks
    struct {
        short comb[2][16][136];         // K cols 0..63, Q cols 64..127
        short vsep[64][40];             // V transposed [h][key 0..31 +pad]
    } c;
};

__global__ __launch_bounds__(256, 2) void proj_fused(
    const float* __restrict__ x, const short* __restrict__ wfrag,
    short* __restrict__ qb, short* __restrict__ kfrag, short* __restrict__ vfrag)
{
    __shared__ __align__(16) ProjSmem sm;

    int tid = threadIdx.x;
    int w = tid >> 6, lane = tid & 63;
    int rt = w >> 1, h = w & 1;
    int l15 = lane & 15, quad = lane >> 4;
    int m0 = blockIdx.x * 32;

    // ---- prefetch wfrag set for ks=0 BEFORE staging (flies during stage) ----
    s16x8 fA[12], fB[12];
    {
        const s16x8* fb = (const s16x8*)&wfrag[((size_t)(h * 16) * 12 * 64 + lane) * 8];
        #pragma unroll
        for (int f = 0; f < 12; ++f) fA[f] = fb[f * 64];
    }

    // ---- stage x: 32 passes, each = one full row, lanes along C ----
    #pragma unroll 8
    for (int p = 0; p < 32; ++p) {
        f32x4 v = *(const f32x4*)&x[(size_t)(m0 + p) * C_DIM + tid * 4];
        u32x2 d;
        d[0] = pack2(v[0], v[1]);
        d[1] = pack2(v[2], v[3]);
        *(u32x2*)&sm.xs[p][tid * 4] = d;
    }
    __syncthreads();

    // ---- MFMA with wfrag double-buffer: wave (rt,h), ksAll = h*16+ks ----
    f32x4 acc[12];
    #pragma unroll
    for (int i = 0; i < 12; ++i) acc[i] = (f32x4){0.f, 0.f, 0.f, 0.f};

    #pragma unroll 1
    for (int ks = 0; ks < 16; ks += 2) {
        {   // prefetch ks+1 into fB
            const s16x8* fb = (const s16x8*)&wfrag[((size_t)(h * 16 + ks + 1) * 12 * 64 + lane) * 8];
            #pragma unroll
            for (int f = 0; f < 12; ++f) fB[f] = fb[f * 64];
        }
        s16x8 af = *(const s16x8*)&sm.xs[rt * 16 + l15][(h * 16 + ks) * 32 + quad * 8];
        #pragma unroll
        for (int f = 0; f < 12; ++f)
            acc[f] = __builtin_amdgcn_mfma_f32_16x16x32_bf16(af, fA[f], acc[f], 0, 0, 0);
        if (ks + 2 < 16) {  // prefetch ks+2 into fA
            const s16x8* fb = (const s16x8*)&wfrag[((size_t)(h * 16 + ks + 2) * 12 * 64 + lane) * 8];
            #pragma unroll
            for (int f = 0; f < 12; ++f) fA[f] = fb[f * 64];
        }
        s16x8 af2 = *(const s16x8*)&sm.xs[rt * 16 + l15][(h * 16 + ks + 1) * 32 + quad * 8];
        #pragma unroll
        for (int f = 0; f < 12; ++f)
            acc[f] = __builtin_amdgcn_mfma_f32_16x16x32_bf16(af2, fB[f], acc[f], 0, 0, 0);
    }
    __syncthreads();   // all waves done reading xs; union -> combine buffers

    // ---- combine: h=1 parks, h=0 adds ----
    if (h == 1) {
        #pragma unroll
        for (int f = 0; f < 8; ++f)
            #pragma unroll
            for (int r = 0; r < 4; ++r)
                sm.c.comb[rt][quad * 4 + r][(f >> 2) * 64 + (f & 3) * 16 + l15] = f2bf(acc[f][r]);
        #pragma unroll
        for (int f = 8; f < 12; ++f)
            #pragma unroll
            for (int r = 0; r < 4; ++r)
                sm.c.vsep[(f & 3) * 16 + l15][rt * 16 + quad * 4 + r] = f2bf(acc[f][r]);
    }
    __syncthreads();
    if (h == 0) {
        #pragma unroll
        for (int f = 0; f < 8; ++f)
            #pragma unroll
            for (int r = 0; r < 4; ++r) {
                int col = (f >> 2) * 64 + (f & 3) * 16 + l15, rr = quad * 4 + r;
                sm.c.comb[rt][rr][col] = f2bf(acc[f][r] + bf2f(sm.c.comb[rt][rr][col]));
            }
        #pragma unroll
        for (int f = 8; f < 12; ++f)
            #pragma unroll
            for (int r = 0; r < 4; ++r) {
                int hh = (f & 3) * 16 + l15, kk = rt * 16 + quad * 4 + r;
                sm.c.vsep[hh][kk] = f2bf(acc[f][r] + bf2f(sm.c.vsep[hh][kk]));
            }
    }
    __syncthreads();

    // ---- emission ----
    int b = m0 >> 12, t0 = m0 & 4095;
    int t016 = t0 >> 4, kt32 = t0 >> 5;
    {   // qb: 32 rows x 64 cols
        int row = tid >> 3, ch = tid & 7;
        s16x8 v = *(const s16x8*)&sm.c.comb[row >> 4][row & 15][64 + ch * 8];
        *(s16x8*)&qb[(size_t)(m0 + row) * 64 + ch * 8] = v;
    }
    {   // kfrag: wave task (kt = w&1, ks = w>>1)
        int kt = w & 1, ks = w >> 1;
        s16x8 v = *(const s16x8*)&sm.c.comb[kt][l15][ks * 32 + quad * 8];
        *(s16x8*)&kfrag[(size_t)(((b * 256 + t016 + kt) * 2 + ks) * 64 + lane) * 8] = v;
    }
    {   // vfrag: wave task nt = w
        int nt = w;
        s16x8 v = *(const s16x8*)&sm.c.vsep[nt * 16 + l15][quad * 8];
        *(s16x8*)&vfrag[(size_t)(((b * 128 + kt32) * 4 + nt) * 64 + lane) * 8] = v;
    }
}

// ---------------------------------------------------------------------------
// Kernel 3: flash partials, S^T form, fixed m=0 softmax. Barrier-free per-wave
// K/V streaming; 32 queries per wave. Next-step loads pinned ahead of compute
// by sched_barrier(0) (compiler cannot sink the double-buffer). Bias tile in
// LDS [32][269]. S->P redistribution in-register via permlane swaps.
// Block = 4 waves = 4 batches. grid (128 g, 16 c) x 256.
// ---------------------------------------------------------------------------
#define SBAR() __builtin_amdgcn_sched_barrier(0)

#define LOADK(AK, k0) do {                                                    \
    int _kt16 = (k0) >> 4;                                                    \
    _Pragma("unroll")                                                         \
    for (int _n = 0; _n < 2; ++_n) {                                          \
        const short* _kp = kfb + (size_t)((_kt16 + _n) * 2) * 512 + lane * 8; \
        AK[_n * 2]     = *(const s16x8*)_kp;                                  \
        AK[_n * 2 + 1] = *(const s16x8*)(_kp + 512);                          \
    }                                                                         \
} while (0)

#define LOADV(BV, k0) do {                                                    \
    int _kt32 = (k0) >> 5;                                                    \
    _Pragma("unroll")                                                         \
    for (int _n = 0; _n < 4; ++_n)                                            \
        BV[_n] = *(const s16x8*)(vfb + (size_t)(_kt32 * 4 + _n) * 512 + lane * 8); \
} while (0)

// RO = blds row offset (0 or 16), Q0S = first query of sub-strip, LS = l_sum
#define SOFT(N, AS, KL, RO, Q0S, LS, PLO, PHI) do {                           \
    f32x4 _vb = *(const f32x4*)&blds[(RO) + l15][(KL) + (N) * 16 + quad * 4]; \
    float _sv[4];                                                             \
    _Pragma("unroll")                                                         \
    for (int _r = 0; _r < 4; ++_r) {                                          \
        _sv[_r] = (AS)[_r] + _vb[_r];                                         \
        if (mask_on && (kabs + (N) * 16 + quad * 4 + _r > (Q0S) + l15))       \
            _sv[_r] = -__builtin_inff();                                      \
        float _p = __expf(_sv[_r]);                                           \
        _sv[_r] = _p;                                                         \
        LS += _p;                                                             \
    }                                                                         \
    PLO = pack2(_sv[0], _sv[1]);                                              \
    PHI = pack2(_sv[2], _sv[3]);                                              \
} while (0)

// In-register S->P(A-frag) redistribution (numerics proven R12-R16):
// (o0,o2)=pl16(pl32(p0,p2)), (o1,o3)=pl16(pl32(p1,p3)).
#define PERM4(P0, P1, P2, P3)                                                 \
    asm("v_permlane32_swap_b32 %0, %1" : "+v"(P0), "+v"(P2));                 \
    asm("v_permlane16_swap_b32 %0, %1" : "+v"(P0), "+v"(P2));                 \
    asm("v_permlane32_swap_b32 %0, %1" : "+v"(P1), "+v"(P3));                 \
    asm("v_permlane16_swap_b32 %0, %1" : "+v"(P1), "+v"(P3));

#define COMPUTEK(AK, BV, k0) do {                                             \
    int _kl = (k0) - kstart;                                                  \
    int kabs = (k0);                                                          \
    f32x4 _aS0 = (f32x4){0.f, 0.f, 0.f, 0.f};                                 \
    f32x4 _aS1 = (f32x4){0.f, 0.f, 0.f, 0.f};                                 \
    f32x4 _aS2 = (f32x4){0.f, 0.f, 0.f, 0.f};                                 \
    f32x4 _aS3 = (f32x4){0.f, 0.f, 0.f, 0.f};                                 \
    _aS0 = __builtin_amdgcn_mfma_f32_16x16x32_bf16(AK[0], aq0, _aS0, 0, 0, 0); \
    _aS0 = __builtin_amdgcn_mfma_f32_16x16x32_bf16(AK[1], aq1, _aS0, 0, 0, 0); \
    _aS1 = __builtin_amdgcn_mfma_f32_16x16x32_bf16(AK[2], aq0, _aS1, 0, 0, 0); \
    _aS1 = __builtin_amdgcn_mfma_f32_16x16x32_bf16(AK[3], aq1, _aS1, 0, 0, 0); \
    _aS2 = __builtin_amdgcn_mfma_f32_16x16x32_bf16(AK[0], aq2, _aS2, 0, 0, 0); \
    _aS2 = __builtin_amdgcn_mfma_f32_16x16x32_bf16(AK[1], aq3, _aS2, 0, 0, 0); \
    _aS3 = __builtin_amdgcn_mfma_f32_16x16x32_bf16(AK[2], aq2, _aS3, 0, 0, 0); \
    _aS3 = __builtin_amdgcn_mfma_f32_16x16x32_bf16(AK[3], aq3, _aS3, 0, 0, 0); \
    unsigned _p0, _p1, _p2, _p3, _p4, _p5, _p6, _p7;                          \
    SOFT(0, _aS0, _kl, 0, q0, l_sum0, _p0, _p1);                              \
    SOFT(1, _aS1, _kl, 0, q0, l_sum0, _p2, _p3);                              \
    SOFT(0, _aS2, _kl, 16, q0 + 16, l_sum1, _p4, _p5);                        \
    SOFT(1, _aS3, _kl, 16, q0 + 16, l_sum1, _p6, _p7);                        \
    PERM4(_p0, _p1, _p2, _p3);                                                \
    PERM4(_p4, _p5, _p6, _p7);                                                \
    u32x4 _apuA = (u32x4){_p0, _p1, _p2, _p3};                                \
    u32x4 _apuB = (u32x4){_p4, _p5, _p6, _p7};                                \
    s16x8 _apA = __builtin_bit_cast(s16x8, _apuA);                            \
    s16x8 _apB = __builtin_bit_cast(s16x8, _apuB);                            \
    _Pragma("unroll")                                                         \
    for (int _n = 0; _n < 4; ++_n) {                                          \
        accO[_n]     = __builtin_amdgcn_mfma_f32_16x16x32_bf16(_apA, BV[_n], accO[_n],     0, 0, 0); \
        accO[_n + 4] = __builtin_amdgcn_mfma_f32_16x16x32_bf16(_apB, BV[_n], accO[_n + 4], 0, 0, 0); \
    }                                                                         \
} while (0)

__global__ __launch_bounds__(256, 3) void flash_part(
    const short* __restrict__ qb, const short* __restrict__ kfrag,
    const short* __restrict__ vfrag, const float* __restrict__ bias,
    short* __restrict__ po)
{
    int g = blockIdx.x, c = blockIdx.y;
    if (c > (g >> 3)) return;                     // block-uniform early exit
    int q0 = g * 32;                              // first query of 32-strip
    int kstart = c * CK;
    int kend = min(kstart + CK, q0 + 32);         // wave-level key end

    __shared__ __align__(16) float blds[32][269]; // bias tile, stride 13 mod 32

    int w = threadIdx.x >> 6, lane = threadIdx.x & 63;  // w = batch
    int b = w;
    int l15 = lane & 15, quad = lane >> 4;

    // ---- stage bias: 8 passes, lanes along keys (1 KB contiguous/inst) ----
    #pragma unroll
    for (int p = 0; p < 8; ++p)
        *(f32x4*)&blds[p * 4 + w][lane * 4] =
            *(const f32x4*)&bias[(size_t)(q0 + p * 4 + w) * T_DIM + kstart + lane * 4];

    const short* qrow = qb + (size_t)(b * T_DIM + q0 + l15) * 64;
    s16x8 aq0 = *(const s16x8*)(qrow + quad * 8);
    s16x8 aq1 = *(const s16x8*)(qrow + 32 + quad * 8);
    const short* qrow2 = qrow + 16 * 64;
    s16x8 aq2 = *(const s16x8*)(qrow2 + quad * 8);
    s16x8 aq3 = *(const s16x8*)(qrow2 + 32 + quad * 8);

    float l_sum0 = 0.f, l_sum1 = 0.f;
    f32x4 accO[8];
    #pragma unroll
    for (int nt = 0; nt < 8; ++nt) accO[nt] = (f32x4){0.f, 0.f, 0.f, 0.f};

    const short* kfb = kfrag + (size_t)b * 256 * 2 * 512;
    const short* vfb = vfrag + (size_t)b * 128 * 4 * 512;
    bool mask_on = (kend > q0);                   // diagonal chunk only

    __syncthreads();                              // bias staged

    // ---- barrier-free k-loop; next-step loads pinned by sched_barrier(0) ----
    s16x8 akA[4], akB[4], bvA[4], bvB[4];
    int k0 = kstart;
    LOADK(akA, k0);
    LOADV(bvA, k0);
    while (true) {
        int k1 = k0 + 32;
        bool more = (k1 < kend);
        if (more) { LOADK(akB, k1); LOADV(bvB, k1); }
        SBAR();                          // loads may not sink past this point
        COMPUTEK(akA, bvA, k0);
        if (!more) break;
        k0 = k1; k1 = k0 + 32;
        bool more2 = (k1 < kend);
        if (more2) { LOADK(akA, k1); LOADV(bvA, k1); }
        SBAR();
        COMPUTEK(akB, bvB, k0);
        if (!more2) break;
        k0 = k1;
    }

    l_sum0 += __shfl_xor(l_sum0, 16, 64);
    l_sum0 += __shfl_xor(l_sum0, 32, 64);
    l_sum1 += __shfl_xor(l_sum1, 16, 64);
    l_sum1 += __shfl_xor(l_sum1, 32, 64);

    short* baseA = po + (size_t)((chunk_off(g * 2) + c) * 4 + b) * 1040;
    #pragma unroll
    for (int nt = 0; nt < 4; ++nt)
        #pragma unroll
        for (int r = 0; r < 4; ++r)
            baseA[(quad * 4 + r) * 64 + nt * 16 + l15] = f2bf(accO[nt][r]);
    if (quad == 0) baseA[1024 + l15] = f2bf(l_sum0);

    short* baseB = po + (size_t)((chunk_off(g * 2 + 1) + c) * 4 + b) * 1040;
    #pragma unroll
    for (int nt = 0; nt < 4; ++nt)
        #pragma unroll
        for (int r = 0; r < 4; ++r)
            baseB[(quad * 4 + r) * 64 + nt * 16 + l15] = f2bf(accO[nt + 4][r]);
    if (quad == 0) baseB[1024 + l15] = f2bf(l_sum1);
}

// ---------------------------------------------------------------------------
// Kernel 4: reduce partials + normalize. 512 x 256, 16B loads (8 thr/row).
// ---------------------------------------------------------------------------
__global__ __launch_bounds__(256) void flash_reduce(
    const short* __restrict__ po, float* __restrict__ out)
{
    int idx = blockIdx.x * 256 + threadIdx.x;     // 131072 = 16384 rows x 8
    int row = idx >> 3, c8 = idx & 7;
    int b = row >> 12, t = row & 4095;
    int qt = t >> 4, rloc = t & 15;
    int nc = (t >> 8) + 1;
    int off = chunk_off(qt);
    float o[8];
    #pragma unroll
    for (int j = 0; j < 8; ++j) o[j] = 0.f;
    float l = 0.f;
    #pragma unroll 1
    for (int cc = 0; cc < nc; ++cc) {
        const short* base = po + (size_t)((off + cc) * 4 + b) * 1040;
        s16x8 v = *(const s16x8*)&base[rloc * 64 + c8 * 8];
        #pragma unroll
        for (int j = 0; j < 8; ++j) o[j] += bf2f(v[j]);
        l += bf2f(base[1024 + rloc]);
    }
    float inv = 1.0f / l;
    f32x4 r0 = (f32x4){o[0] * inv, o[1] * inv, o[2] * inv, o[3] * inv};
    f32x4 r1 = (f32x4){o[4] * inv, o[5] * inv, o[6] * inv, o[7] * inv};
    float* op = &out[(size_t)row * 64 + c8 * 8];
    *(f32x4*)op = r0;
    *(f32x4*)(op + 4) = r1;
}

// ---------------------------------------------------------------------------
extern "C" void kernel_launch(void* const* d_in, const int* in_sizes, int n_in,
                              void* d_out, int out_size, void* d_ws, size_t ws_size,
                              hipStream_t stream) {
    (void)in_sizes; (void)n_in; (void)out_size; (void)ws_size;
    const float* x    = (const float*)d_in[0];
    const float* bias = (const float*)d_in[1];
    const float* wk   = (const float*)d_in[2];
    const float* wq   = (const float*)d_in[3];
    const float* wv   = (const float*)d_in[4];
    float* out = (float*)d_out;

    short* wfrag = (short*)d_ws;                       // 196608
    short* qb    = wfrag + 196608;                     // 1048576 each
    short* kfrag = qb + 1048576;
    short* vfrag = kfrag + 1048576;
    short* po    = vfrag + 1048576;                    // 2176*4*1040 = 9052160

    prep_frag<<<dim3(32, 3), dim3(256), 0, stream>>>(wk, wq, wv, wfrag);
    proj_fused<<<dim3(512), dim3(256), 0, stream>>>(x, wfrag, qb, kfrag, vfrag);
    flash_part<<<dim3(128, 16), dim3(256), 0, stream>>>(qb, kfrag, vfrag, bias, po);
    flash_reduce<<<dim3(512), dim3(256), 0, stream>>>(po, out);
}

// Round 9
// 193.472 us; speedup vs baseline: 1.0005x; 1.0005x over previous
//
#include <hip/hip_runtime.h>
#include <hip/hip_bf16.h>

// B=4, T=4096, C=1024, H=64 causal attention w/ RPE bias.
// Round 18: R17's sched_barrier(0) did NOT bind (VGPR stayed 84 -> K/V dbuf
// sunk by a pre-RA pass that ignores the fence; 43us unchanged). This round
// the k-loop loads are taken away from the compiler: K/V issued as
// asm volatile global_load_dwordx4 ("=&v") — unsinkable, unfoldable — with
// manual counted s_waitcnt vmcnt(8) (next step's 8 loads stay in flight
// through every COMPUTEK; vmcnt(0) only at the tail) + sched_barrier(0)
// after each wait (rule 18: stop MFMA hoisting above it). Loop has zero
// compiler-tracked VMEM (bias=LDS, po stores post-loop), so compiler waitcnt
// bookkeeping never touches the asm queue; prologue asm issue sits after
// __syncthreads so the barrier drain isolates it from compiler prologue
// loads. Everything else identical to R17 (QBLK32, blds[32][269], permlane).

#define T_DIM 4096
#define C_DIM 1024
#define CK    256          // flash key-chunk (keys per po partial)

typedef __attribute__((ext_vector_type(8))) short s16x8;
typedef __attribute__((ext_vector_type(4))) float f32x4;
typedef __attribute__((ext_vector_type(2))) unsigned int u32x2;
typedef __attribute__((ext_vector_type(4))) unsigned int u32x4;

__device__ __forceinline__ short f2bf(float f) {
    unsigned u = __builtin_bit_cast(unsigned, f);
    u += 0x7FFFu + ((u >> 16) & 1u);
    return (short)(u >> 16);
}
__device__ __forceinline__ unsigned pack2(float a, float b) {
    unsigned ua = __builtin_bit_cast(unsigned, a);
    unsigned ub = __builtin_bit_cast(unsigned, b);
    ua += 0x7FFFu + ((ua >> 16) & 1u);
    ub += 0x7FFFu + ((ub >> 16) & 1u);
    return __builtin_amdgcn_perm(ub, ua, 0x07060302u);
}
__device__ __forceinline__ float bf2f(short s) {
    unsigned u = ((unsigned)(unsigned short)s) << 16;
    return __builtin_bit_cast(float, u);
}
// prefix of active 256-key chunks before 16-q-strip qt: nchunks(j)=j/16+1
__device__ __forceinline__ int chunk_off(int qt) {
    int g = qt >> 4, r = qt & 15;
    return qt + 8 * g * (g - 1) + r * g;
}

// ---------------------------------------------------------------------------
// Kernel 1: weights -> B-fragment order: wfrag[ksAll][mat][nt][lane][8] bf16.
// w_q scaled by 0.125. grid (32, 3) x 256.
// ---------------------------------------------------------------------------
__global__ __launch_bounds__(256) void prep_frag(
    const float* __restrict__ wk, const float* __restrict__ wq,
    const float* __restrict__ wv, short* __restrict__ wfrag)
{
    int ksAll = blockIdx.x, mat = blockIdx.y;
    const float* w = (mat == 0) ? wk : ((mat == 1) ? wq : wv);
    float sc = (mat == 1) ? 0.125f : 1.0f;
    int nt = threadIdx.x >> 6, lane = threadIdx.x & 63;
    int quad = lane >> 4, l15 = lane & 15;
    int h = nt * 16 + l15;
    int cb = ksAll * 32 + quad * 8;
    s16x8 v;
    #pragma unroll
    for (int j = 0; j < 8; ++j) v[j] = f2bf(w[(cb + j) * 64 + h] * sc);
    *(s16x8*)&wfrag[((ksAll * 12 + mat * 4 + nt) * 64 + lane) * 8] = v;
}

// ---------------------------------------------------------------------------
// Kernel 2: fused projection, 32 rows/block, x staged coalesced into LDS,
// wfrag B-fragments double-buffered in registers (L2-latency hiding).
// grid 512 x 256 (4 waves = 2 row-tiles x 2 C-halves).
// ---------------------------------------------------------------------------
union ProjSmem {
    short xs[32][1032];                 // staged x rows (bf16); 1032 pad -> 2-way banks
    struct {
        short comb[2][16][136];         // K cols 0..63, Q cols 64..127
        short vsep[64][40];             // V transposed [h][key 0..31 +pad]
    } c;
};

__global__ __launch_bounds__(256, 2) void proj_fused(
    const float* __restrict__ x, const short* __restrict__ wfrag,
    short* __restrict__ qb, short* __restrict__ kfrag, short* __restrict__ vfrag)
{
    __shared__ __align__(16) ProjSmem sm;

    int tid = threadIdx.x;
    int w = tid >> 6, lane = tid & 63;
    int rt = w >> 1, h = w & 1;
    int l15 = lane & 15, quad = lane >> 4;
    int m0 = blockIdx.x * 32;

    // ---- prefetch wfrag set for ks=0 BEFORE staging (flies during stage) ----
    s16x8 fA[12], fB[12];
    {
        const s16x8* fb = (const s16x8*)&wfrag[((size_t)(h * 16) * 12 * 64 + lane) * 8];
        #pragma unroll
        for (int f = 0; f < 12; ++f) fA[f] = fb[f * 64];
    }

    // ---- stage x: 32 passes, each = one full row, lanes along C ----
    #pragma unroll 8
    for (int p = 0; p < 32; ++p) {
        f32x4 v = *(const f32x4*)&x[(size_t)(m0 + p) * C_DIM + tid * 4];
        u32x2 d;
        d[0] = pack2(v[0], v[1]);
        d[1] = pack2(v[2], v[3]);
        *(u32x2*)&sm.xs[p][tid * 4] = d;
    }
    __syncthreads();

    // ---- MFMA with wfrag double-buffer: wave (rt,h), ksAll = h*16+ks ----
    f32x4 acc[12];
    #pragma unroll
    for (int i = 0; i < 12; ++i) acc[i] = (f32x4){0.f, 0.f, 0.f, 0.f};

    #pragma unroll 1
    for (int ks = 0; ks < 16; ks += 2) {
        {   // prefetch ks+1 into fB
            const s16x8* fb = (const s16x8*)&wfrag[((size_t)(h * 16 + ks + 1) * 12 * 64 + lane) * 8];
            #pragma unroll
            for (int f = 0; f < 12; ++f) fB[f] = fb[f * 64];
        }
        s16x8 af = *(const s16x8*)&sm.xs[rt * 16 + l15][(h * 16 + ks) * 32 + quad * 8];
        #pragma unroll
        for (int f = 0; f < 12; ++f)
            acc[f] = __builtin_amdgcn_mfma_f32_16x16x32_bf16(af, fA[f], acc[f], 0, 0, 0);
        if (ks + 2 < 16) {  // prefetch ks+2 into fA
            const s16x8* fb = (const s16x8*)&wfrag[((size_t)(h * 16 + ks + 2) * 12 * 64 + lane) * 8];
            #pragma unroll
            for (int f = 0; f < 12; ++f) fA[f] = fb[f * 64];
        }
        s16x8 af2 = *(const s16x8*)&sm.xs[rt * 16 + l15][(h * 16 + ks + 1) * 32 + quad * 8];
        #pragma unroll
        for (int f = 0; f < 12; ++f)
            acc[f] = __builtin_amdgcn_mfma_f32_16x16x32_bf16(af2, fB[f], acc[f], 0, 0, 0);
    }
    __syncthreads();   // all waves done reading xs; union -> combine buffers

    // ---- combine: h=1 parks, h=0 adds ----
    if (h == 1) {
        #pragma unroll
        for (int f = 0; f < 8; ++f)
            #pragma unroll
            for (int r = 0; r < 4; ++r)
                sm.c.comb[rt][quad * 4 + r][(f >> 2) * 64 + (f & 3) * 16 + l15] = f2bf(acc[f][r]);
        #pragma unroll
        for (int f = 8; f < 12; ++f)
            #pragma unroll
            for (int r = 0; r < 4; ++r)
                sm.c.vsep[(f & 3) * 16 + l15][rt * 16 + quad * 4 + r] = f2bf(acc[f][r]);
    }
    __syncthreads();
    if (h == 0) {
        #pragma unroll
        for (int f = 0; f < 8; ++f)
            #pragma unroll
            for (int r = 0; r < 4; ++r) {
                int col = (f >> 2) * 64 + (f & 3) * 16 + l15, rr = quad * 4 + r;
                sm.c.comb[rt][rr][col] = f2bf(acc[f][r] + bf2f(sm.c.comb[rt][rr][col]));
            }
        #pragma unroll
        for (int f = 8; f < 12; ++f)
            #pragma unroll
            for (int r = 0; r < 4; ++r) {
                int hh = (f & 3) * 16 + l15, kk = rt * 16 + quad * 4 + r;
                sm.c.vsep[hh][kk] = f2bf(acc[f][r] + bf2f(sm.c.vsep[hh][kk]));
            }
    }
    __syncthreads();

    // ---- emission ----
    int b = m0 >> 12, t0 = m0 & 4095;
    int t016 = t0 >> 4, kt32 = t0 >> 5;
    {   // qb: 32 rows x 64 cols
        int row = tid >> 3, ch = tid & 7;
        s16x8 v = *(const s16x8*)&sm.c.comb[row >> 4][row & 15][64 + ch * 8];
        *(s16x8*)&qb[(size_t)(m0 + row) * 64 + ch * 8] = v;
    }
    {   // kfrag: wave task (kt = w&1, ks = w>>1)
        int kt = w & 1, ks = w >> 1;
        s16x8 v = *(const s16x8*)&sm.c.comb[kt][l15][ks * 32 + quad * 8];
        *(s16x8*)&kfrag[(size_t)(((b * 256 + t016 + kt) * 2 + ks) * 64 + lane) * 8] = v;
    }
    {   // vfrag: wave task nt = w
        int nt = w;
        s16x8 v = *(const s16x8*)&sm.c.vsep[nt * 16 + l15][quad * 8];
        *(s16x8*)&vfrag[(size_t)(((b * 128 + kt32) * 4 + nt) * 64 + lane) * 8] = v;
    }
}

// ---------------------------------------------------------------------------
// Kernel 3: flash partials, S^T form, fixed m=0 softmax. Barrier-free per-wave
// K/V streaming; 32 queries per wave. K/V loads issued as asm volatile
// global_load_dwordx4 (unsinkable double-buffer), manual counted
// s_waitcnt vmcnt(8) + sched_barrier(0). Bias tile in LDS [32][269].
// S->P redistribution in-register via permlane swaps.
// Block = 4 waves = 4 batches. grid (128 g, 16 c) x 256.
// ---------------------------------------------------------------------------
#define ALOAD4(A0, A1, A2, A3, AD) do {                                       \
    asm volatile("global_load_dwordx4 %0, %1, off"                            \
                 : "=&v"(A0) : "v"(AD));                                      \
    asm volatile("global_load_dwordx4 %0, %1, off offset:1024"                \
                 : "=&v"(A1) : "v"(AD));                                      \
    asm volatile("global_load_dwordx4 %0, %1, off offset:2048"                \
                 : "=&v"(A2) : "v"(AD));                                      \
    asm volatile("global_load_dwordx4 %0, %1, off offset:3072"                \
                 : "=&v"(A3) : "v"(AD));                                      \
} while (0)

#define WAITV8() do { asm volatile("s_waitcnt vmcnt(8)");                     \
                      __builtin_amdgcn_sched_barrier(0); } while (0)
#define WAITV0() do { asm volatile("s_waitcnt vmcnt(0)");                     \
                      __builtin_amdgcn_sched_barrier(0); } while (0)

// RO = blds row offset (0 or 16), Q0S = first query of sub-strip, LS = l_sum
#define SOFT(N, AS, KL, RO, Q0S, LS, PLO, PHI) do {                           \
    f32x4 _vb = *(const f32x4*)&blds[(RO) + l15][(KL) + (N) * 16 + quad * 4]; \
    float _sv[4];                                                             \
    _Pragma("unroll")                                                         \
    for (int _r = 0; _r < 4; ++_r) {                                          \
        _sv[_r] = (AS)[_r] + _vb[_r];                                         \
        if (mask_on && (kabs + (N) * 16 + quad * 4 + _r > (Q0S) + l15))       \
            _sv[_r] = -__builtin_inff();                                      \
        float _p = __expf(_sv[_r]);                                           \
        _sv[_r] = _p;                                                         \
        LS += _p;                                                             \
    }                                                                         \
    PLO = pack2(_sv[0], _sv[1]);                                              \
    PHI = pack2(_sv[2], _sv[3]);                                              \
} while (0)

// In-register S->P(A-frag) redistribution (numerics proven R12-R17):
// (o0,o2)=pl16(pl32(p0,p2)), (o1,o3)=pl16(pl32(p1,p3)).
#define PERM4(P0, P1, P2, P3)                                                 \
    asm("v_permlane32_swap_b32 %0, %1" : "+v"(P0), "+v"(P2));                 \
    asm("v_permlane16_swap_b32 %0, %1" : "+v"(P0), "+v"(P2));                 \
    asm("v_permlane32_swap_b32 %0, %1" : "+v"(P1), "+v"(P3));                 \
    asm("v_permlane16_swap_b32 %0, %1" : "+v"(P1), "+v"(P3));

#define COMPUTEK(AK, BV, k0) do {                                             \
    int _kl = (k0) - kstart;                                                  \
    int kabs = (k0);                                                          \
    f32x4 _aS0 = (f32x4){0.f, 0.f, 0.f, 0.f};                                 \
    f32x4 _aS1 = (f32x4){0.f, 0.f, 0.f, 0.f};                                 \
    f32x4 _aS2 = (f32x4){0.f, 0.f, 0.f, 0.f};                                 \
    f32x4 _aS3 = (f32x4){0.f, 0.f, 0.f, 0.f};                                 \
    _aS0 = __builtin_amdgcn_mfma_f32_16x16x32_bf16(AK[0], aq0, _aS0, 0, 0, 0); \
    _aS0 = __builtin_amdgcn_mfma_f32_16x16x32_bf16(AK[1], aq1, _aS0, 0, 0, 0); \
    _aS1 = __builtin_amdgcn_mfma_f32_16x16x32_bf16(AK[2], aq0, _aS1, 0, 0, 0); \
    _aS1 = __builtin_amdgcn_mfma_f32_16x16x32_bf16(AK[3], aq1, _aS1, 0, 0, 0); \
    _aS2 = __builtin_amdgcn_mfma_f32_16x16x32_bf16(AK[0], aq2, _aS2, 0, 0, 0); \
    _aS2 = __builtin_amdgcn_mfma_f32_16x16x32_bf16(AK[1], aq3, _aS2, 0, 0, 0); \
    _aS3 = __builtin_amdgcn_mfma_f32_16x16x32_bf16(AK[2], aq2, _aS3, 0, 0, 0); \
    _aS3 = __builtin_amdgcn_mfma_f32_16x16x32_bf16(AK[3], aq3, _aS3, 0, 0, 0); \
    unsigned _p0, _p1, _p2, _p3, _p4, _p5, _p6, _p7;                          \
    SOFT(0, _aS0, _kl, 0, q0, l_sum0, _p0, _p1);                              \
    SOFT(1, _aS1, _kl, 0, q0, l_sum0, _p2, _p3);                              \
    SOFT(0, _aS2, _kl, 16, q0 + 16, l_sum1, _p4, _p5);                        \
    SOFT(1, _aS3, _kl, 16, q0 + 16, l_sum1, _p6, _p7);                        \
    PERM4(_p0, _p1, _p2, _p3);                                                \
    PERM4(_p4, _p5, _p6, _p7);                                                \
    u32x4 _apuA = (u32x4){_p0, _p1, _p2, _p3};                                \
    u32x4 _apuB = (u32x4){_p4, _p5, _p6, _p7};                                \
    s16x8 _apA = __builtin_bit_cast(s16x8, _apuA);                            \
    s16x8 _apB = __builtin_bit_cast(s16x8, _apuB);                            \
    _Pragma("unroll")                                                         \
    for (int _n = 0; _n < 4; ++_n) {                                          \
        accO[_n]     = __builtin_amdgcn_mfma_f32_16x16x32_bf16(_apA, BV[_n], accO[_n],     0, 0, 0); \
        accO[_n + 4] = __builtin_amdgcn_mfma_f32_16x16x32_bf16(_apB, BV[_n], accO[_n + 4], 0, 0, 0); \
    }                                                                         \
} while (0)

__global__ __launch_bounds__(256, 3) void flash_part(
    const short* __restrict__ qb, const short* __restrict__ kfrag,
    const short* __restrict__ vfrag, const float* __restrict__ bias,
    short* __restrict__ po)
{
    int g = blockIdx.x, c = blockIdx.y;
    if (c > (g >> 3)) return;                     // block-uniform early exit
    int q0 = g * 32;                              // first query of 32-strip
    int kstart = c * CK;
    int kend = min(kstart + CK, q0 + 32);         // wave-level key end

    __shared__ __align__(16) float blds[32][269]; // bias tile, stride 13 mod 32

    int w = threadIdx.x >> 6, lane = threadIdx.x & 63;  // w = batch
    int b = w;
    int l15 = lane & 15, quad = lane >> 4;

    // ---- stage bias: 8 passes, lanes along keys (1 KB contiguous/inst) ----
    #pragma unroll
    for (int p = 0; p < 8; ++p)
        *(f32x4*)&blds[p * 4 + w][lane * 4] =
            *(const f32x4*)&bias[(size_t)(q0 + p * 4 + w) * T_DIM + kstart + lane * 4];

    const short* qrow = qb + (size_t)(b * T_DIM + q0 + l15) * 64;
    s16x8 aq0 = *(const s16x8*)(qrow + quad * 8);
    s16x8 aq1 = *(const s16x8*)(qrow + 32 + quad * 8);
    const short* qrow2 = qrow + 16 * 64;
    s16x8 aq2 = *(const s16x8*)(qrow2 + quad * 8);
    s16x8 aq3 = *(const s16x8*)(qrow2 + 32 + quad * 8);

    float l_sum0 = 0.f, l_sum1 = 0.f;
    f32x4 accO[8];
    #pragma unroll
    for (int nt = 0; nt < 8; ++nt) accO[nt] = (f32x4){0.f, 0.f, 0.f, 0.f};

    const short* kfb = kfrag + (size_t)b * 256 * 2 * 512;
    const short* vfb = vfrag + (size_t)b * 128 * 4 * 512;
    bool mask_on = (kend > q0);                   // diagonal chunk only

    __syncthreads();                              // bias staged; vmem drained

    // ---- asm-pipelined barrier-free k-loop: 8 loads always in flight ----
    // step byte stride = 4 KB for both K and V (krel*128).
    const char* kadd = (const char*)kfb + (size_t)kstart * 128 + lane * 16;
    const char* vadd = (const char*)vfb + (size_t)kstart * 128 + lane * 16;
    s16x8 akA[4], akB[4], bvA[4], bvB[4];
    ALOAD4(akA[0], akA[1], akA[2], akA[3], kadd);
    ALOAD4(bvA[0], bvA[1], bvA[2], bvA[3], vadd);

    int nk = kend - kstart;
    int krel = 0;
    while (true) {
        bool more = (krel + 32 < nk);
        if (more) {
            const char* ka = kadd + (size_t)(krel + 32) * 128;
            const char* va = vadd + (size_t)(krel + 32) * 128;
            ALOAD4(akB[0], akB[1], akB[2], akB[3], ka);
            ALOAD4(bvB[0], bvB[1], bvB[2], bvB[3], va);
            WAITV8();                    // current step landed; next in flight
        } else {
            WAITV0();
        }
        COMPUTEK(akA, bvA, kstart + krel);
        if (!more) break;
        krel += 32;
        bool more2 = (krel + 32 < nk);
        if (more2) {
            const char* ka = kadd + (size_t)(krel + 32) * 128;
            const char* va = vadd + (size_t)(krel + 32) * 128;
            ALOAD4(akA[0], akA[1], akA[2], akA[3], ka);
            ALOAD4(bvA[0], bvA[1], bvA[2], bvA[3], va);
            WAITV8();
        } else {
            WAITV0();
        }
        COMPUTEK(akB, bvB, kstart + krel);
        if (!more2) break;
        krel += 32;
    }

    l_sum0 += __shfl_xor(l_sum0, 16, 64);
    l_sum0 += __shfl_xor(l_sum0, 32, 64);
    l_sum1 += __shfl_xor(l_sum1, 16, 64);
    l_sum1 += __shfl_xor(l_sum1, 32, 64);

    short* baseA = po + (size_t)((chunk_off(g * 2) + c) * 4 + b) * 1040;
    #pragma unroll
    for (int nt = 0; nt < 4; ++nt)
        #pragma unroll
        for (int r = 0; r < 4; ++r)
            baseA[(quad * 4 + r) * 64 + nt * 16 + l15] = f2bf(accO[nt][r]);
    if (quad == 0) baseA[1024 + l15] = f2bf(l_sum0);

    short* baseB = po + (size_t)((chunk_off(g * 2 + 1) + c) * 4 + b) * 1040;
    #pragma unroll
    for (int nt = 0; nt < 4; ++nt)
        #pragma unroll
        for (int r = 0; r < 4; ++r)
            baseB[(quad * 4 + r) * 64 + nt * 16 + l15] = f2bf(accO[nt + 4][r]);
    if (quad == 0) baseB[1024 + l15] = f2bf(l_sum1);
}

// ---------------------------------------------------------------------------
// Kernel 4: reduce partials + normalize. 512 x 256, 16B loads (8 thr/row).
// ---------------------------------------------------------------------------
__global__ __launch_bounds__(256) void flash_reduce(
    const short* __restrict__ po, float* __restrict__ out)
{
    int idx = blockIdx.x * 256 + threadIdx.x;     // 131072 = 16384 rows x 8
    int row = idx >> 3, c8 = idx & 7;
    int b = row >> 12, t = row & 4095;
    int qt = t >> 4, rloc = t & 15;
    int nc = (t >> 8) + 1;
    int off = chunk_off(qt);
    float o[8];
    #pragma unroll
    for (int j = 0; j < 8; ++j) o[j] = 0.f;
    float l = 0.f;
    #pragma unroll 1
    for (int cc = 0; cc < nc; ++cc) {
        const short* base = po + (size_t)((off + cc) * 4 + b) * 1040;
        s16x8 v = *(const s16x8*)&base[rloc * 64 + c8 * 8];
        #pragma unroll
        for (int j = 0; j < 8; ++j) o[j] += bf2f(v[j]);
        l += bf2f(base[1024 + rloc]);
    }
    float inv = 1.0f / l;
    f32x4 r0 = (f32x4){o[0] * inv, o[1] * inv, o[2] * inv, o[3] * inv};
    f32x4 r1 = (f32x4){o[4] * inv, o[5] * inv, o[6] * inv, o[7] * inv};
    float* op = &out[(size_t)row * 64 + c8 * 8];
    *(f32x4*)op = r0;
    *(f32x4*)(op + 4) = r1;
}

// ---------------------------------------------------------------------------
extern "C" void kernel_launch(void* const* d_in, const int* in_sizes, int n_in,
                              void* d_out, int out_size, void* d_ws, size_t ws_size,
                              hipStream_t stream) {
    (void)in_sizes; (void)n_in; (void)out_size; (void)ws_size;
    const float* x    = (const float*)d_in[0];
    const float* bias = (const float*)d_in[1];
    const float* wk   = (const float*)d_in[2];
    const float* wq   = (const float*)d_in[3];
    const float* wv   = (const float*)d_in[4];
    float* out = (float*)d_out;

    short* wfrag = (short*)d_ws;                       // 196608
    short* qb    = wfrag + 196608;                     // 1048576 each
    short* kfrag = qb + 1048576;
    short* vfrag = kfrag + 1048576;
    short* po    = vfrag + 1048576;                    // 2176*4*1040 = 9052160

    prep_frag<<<dim3(32, 3), dim3(256), 0, stream>>>(wk, wq, wv, wfrag);
    proj_fused<<<dim3(512), dim3(256), 0, stream>>>(x, wfrag, qb, kfrag, vfrag);
    flash_part<<<dim3(128, 16), dim3(256), 0, stream>>>(qb, kfrag, vfrag, bias, po);
    flash_reduce<<<dim3(512), dim3(256), 0, stream>>>(po, out);
}

// Round 10
// 192.580 us; speedup vs baseline: 1.0051x; 1.0046x over previous
//
#include <hip/hip_runtime.h>
#include <hip/hip_bf16.h>

// B=4, T=4096, C=1024, H=64 causal attention w/ RPE bias.
// Round 19: R18's asm-volatile counted-vmcnt pipeline WORKED on flash_part
// (left top-5; 43.4 -> <40.6us). New top dispatch: proj_fused 41.6us with
// VALUBusy 6.3% / MfmaUtil 5.4% / VGPR 88 — the same compiler-sunk-prefetch
// disease (fA+fB need 96 VGPRs; allocator kept 88 total). Fix = same
// medicine: wfrag loads issued as asm volatile global_load_dwordx4 ("=&v",
// unsinkable), manual s_waitcnt vmcnt(12) + sched_barrier(0) per half-step,
// 12-24 loads always in flight, vmcnt(0) only at the tail. The k-loop has
// zero compiler-tracked VMEM (x staged to LDS before the barrier; emission
// after the loop), so compiler waitcnt bookkeeping never touches the asm
// queue. fA prologue issue moved after __syncthreads (clean vmcnt slate;
// costs one exposed L2 trip per block). flash_part/prep/reduce = R18.

#define T_DIM 4096
#define C_DIM 1024
#define CK    256          // flash key-chunk (keys per po partial)

typedef __attribute__((ext_vector_type(8))) short s16x8;
typedef __attribute__((ext_vector_type(4))) float f32x4;
typedef __attribute__((ext_vector_type(2))) unsigned int u32x2;
typedef __attribute__((ext_vector_type(4))) unsigned int u32x4;

__device__ __forceinline__ short f2bf(float f) {
    unsigned u = __builtin_bit_cast(unsigned, f);
    u += 0x7FFFu + ((u >> 16) & 1u);
    return (short)(u >> 16);
}
__device__ __forceinline__ unsigned pack2(float a, float b) {
    unsigned ua = __builtin_bit_cast(unsigned, a);
    unsigned ub = __builtin_bit_cast(unsigned, b);
    ua += 0x7FFFu + ((ua >> 16) & 1u);
    ub += 0x7FFFu + ((ub >> 16) & 1u);
    return __builtin_amdgcn_perm(ub, ua, 0x07060302u);
}
__device__ __forceinline__ float bf2f(short s) {
    unsigned u = ((unsigned)(unsigned short)s) << 16;
    return __builtin_bit_cast(float, u);
}
// prefix of active 256-key chunks before 16-q-strip qt: nchunks(j)=j/16+1
__device__ __forceinline__ int chunk_off(int qt) {
    int g = qt >> 4, r = qt & 15;
    return qt + 8 * g * (g - 1) + r * g;
}

// ---- asm-volatile load primitives (unsinkable; manual vmcnt discipline) ----
#define ALOAD4(A0, A1, A2, A3, AD) do {                                       \
    asm volatile("global_load_dwordx4 %0, %1, off"                            \
                 : "=&v"(A0) : "v"(AD));                                      \
    asm volatile("global_load_dwordx4 %0, %1, off offset:1024"                \
                 : "=&v"(A1) : "v"(AD));                                      \
    asm volatile("global_load_dwordx4 %0, %1, off offset:2048"                \
                 : "=&v"(A2) : "v"(AD));                                      \
    asm volatile("global_load_dwordx4 %0, %1, off offset:3072"                \
                 : "=&v"(A3) : "v"(AD));                                      \
} while (0)

#define WAITV12() do { asm volatile("s_waitcnt vmcnt(12)");                   \
                       __builtin_amdgcn_sched_barrier(0); } while (0)
#define WAITV8()  do { asm volatile("s_waitcnt vmcnt(8)");                    \
                       __builtin_amdgcn_sched_barrier(0); } while (0)
#define WAITV0()  do { asm volatile("s_waitcnt vmcnt(0)");                    \
                       __builtin_amdgcn_sched_barrier(0); } while (0)

// ---------------------------------------------------------------------------
// Kernel 1: weights -> B-fragment order: wfrag[ksAll][mat][nt][lane][8] bf16.
// w_q scaled by 0.125. grid (32, 3) x 256.
// ---------------------------------------------------------------------------
__global__ __launch_bounds__(256) void prep_frag(
    const float* __restrict__ wk, const float* __restrict__ wq,
    const float* __restrict__ wv, short* __restrict__ wfrag)
{
    int ksAll = blockIdx.x, mat = blockIdx.y;
    const float* w = (mat == 0) ? wk : ((mat == 1) ? wq : wv);
    float sc = (mat == 1) ? 0.125f : 1.0f;
    int nt = threadIdx.x >> 6, lane = threadIdx.x & 63;
    int quad = lane >> 4, l15 = lane & 15;
    int h = nt * 16 + l15;
    int cb = ksAll * 32 + quad * 8;
    s16x8 v;
    #pragma unroll
    for (int j = 0; j < 8; ++j) v[j] = f2bf(w[(cb + j) * 64 + h] * sc);
    *(s16x8*)&wfrag[((ksAll * 12 + mat * 4 + nt) * 64 + lane) * 8] = v;
}

// ---------------------------------------------------------------------------
// Kernel 2: fused projection, 32 rows/block, x staged coalesced into LDS.
// wfrag B-fragments double-buffered in registers via ASM VOLATILE loads
// (12 loads/step, vmcnt(12) counted waits — compiler cannot sink them).
// grid 512 x 256 (4 waves = 2 row-tiles x 2 C-halves).
// ---------------------------------------------------------------------------
union ProjSmem {
    short xs[32][1032];                 // staged x rows (bf16); 1032 pad -> 2-way banks
    struct {
        short comb[2][16][136];         // K cols 0..63, Q cols 64..127
        short vsep[64][40];             // V transposed [h][key 0..31 +pad]
    } c;
};

// issue 12 wfrag fragment loads for one ks step (f stride = 1024 B)
#define WLOAD12(F, BASE) do {                                                 \
    const char* _b0 = (BASE);                                                 \
    ALOAD4((F)[0], (F)[1], (F)[2],  (F)[3],  _b0);                            \
    ALOAD4((F)[4], (F)[5], (F)[6],  (F)[7],  _b0 + 4096);                     \
    ALOAD4((F)[8], (F)[9], (F)[10], (F)[11], _b0 + 8192);                     \
} while (0)

__global__ __launch_bounds__(256, 2) void proj_fused(
    const float* __restrict__ x, const short* __restrict__ wfrag,
    short* __restrict__ qb, short* __restrict__ kfrag, short* __restrict__ vfrag)
{
    __shared__ __align__(16) ProjSmem sm;

    int tid = threadIdx.x;
    int w = tid >> 6, lane = tid & 63;
    int rt = w >> 1, h = w & 1;
    int l15 = lane & 15, quad = lane >> 4;
    int m0 = blockIdx.x * 32;

    // ---- stage x: 32 passes, each = one full row, lanes along C ----
    #pragma unroll 8
    for (int p = 0; p < 32; ++p) {
        f32x4 v = *(const f32x4*)&x[(size_t)(m0 + p) * C_DIM + tid * 4];
        u32x2 d;
        d[0] = pack2(v[0], v[1]);
        d[1] = pack2(v[2], v[3]);
        *(u32x2*)&sm.xs[p][tid * 4] = d;
    }
    __syncthreads();                    // staging done; vmcnt slate clean

    // ---- MFMA loop: asm-pipelined wfrag double-buffer, vmcnt(12) waits ----
    f32x4 acc[12];
    #pragma unroll
    for (int i = 0; i < 12; ++i) acc[i] = (f32x4){0.f, 0.f, 0.f, 0.f};

    // byte layout: frag(ksAll, f) at ksAll*12288 + f*1024 + lane*16
    const char* wbase = (const char*)wfrag + (size_t)(h * 16) * 12288 + lane * 16;
    s16x8 fA[12], fB[12];
    WLOAD12(fA, wbase);                 // ks=0 in flight

    int ks = 0;
    while (true) {
        WLOAD12(fB, wbase + (size_t)(ks + 1) * 12288);   // ks+1 in flight
        WAITV12();                                       // fA (ks) landed
        s16x8 af = *(const s16x8*)&sm.xs[rt * 16 + l15][(h * 16 + ks) * 32 + quad * 8];
        #pragma unroll
        for (int f = 0; f < 12; ++f)
            acc[f] = __builtin_amdgcn_mfma_f32_16x16x32_bf16(af, fA[f], acc[f], 0, 0, 0);
        if (ks + 2 < 16) {
            WLOAD12(fA, wbase + (size_t)(ks + 2) * 12288);
            WAITV12();                                   // fB (ks+1) landed
        } else {
            WAITV0();
        }
        s16x8 af2 = *(const s16x8*)&sm.xs[rt * 16 + l15][(h * 16 + ks + 1) * 32 + quad * 8];
        #pragma unroll
        for (int f = 0; f < 12; ++f)
            acc[f] = __builtin_amdgcn_mfma_f32_16x16x32_bf16(af2, fB[f], acc[f], 0, 0, 0);
        ks += 2;
        if (ks >= 16) break;
    }
    __syncthreads();   // all waves done reading xs; union -> combine buffers

    // ---- combine: h=1 parks, h=0 adds ----
    if (h == 1) {
        #pragma unroll
        for (int f = 0; f < 8; ++f)
            #pragma unroll
            for (int r = 0; r < 4; ++r)
                sm.c.comb[rt][quad * 4 + r][(f >> 2) * 64 + (f & 3) * 16 + l15] = f2bf(acc[f][r]);
        #pragma unroll
        for (int f = 8; f < 12; ++f)
            #pragma unroll
            for (int r = 0; r < 4; ++r)
                sm.c.vsep[(f & 3) * 16 + l15][rt * 16 + quad * 4 + r] = f2bf(acc[f][r]);
    }
    __syncthreads();
    if (h == 0) {
        #pragma unroll
        for (int f = 0; f < 8; ++f)
            #pragma unroll
            for (int r = 0; r < 4; ++r) {
                int col = (f >> 2) * 64 + (f & 3) * 16 + l15, rr = quad * 4 + r;
                sm.c.comb[rt][rr][col] = f2bf(acc[f][r] + bf2f(sm.c.comb[rt][rr][col]));
            }
        #pragma unroll
        for (int f = 8; f < 12; ++f)
            #pragma unroll
            for (int r = 0; r < 4; ++r) {
                int hh = (f & 3) * 16 + l15, kk = rt * 16 + quad * 4 + r;
                sm.c.vsep[hh][kk] = f2bf(acc[f][r] + bf2f(sm.c.vsep[hh][kk]));
            }
    }
    __syncthreads();

    // ---- emission ----
    int b = m0 >> 12, t0 = m0 & 4095;
    int t016 = t0 >> 4, kt32 = t0 >> 5;
    {   // qb: 32 rows x 64 cols
        int row = tid >> 3, ch = tid & 7;
        s16x8 v = *(const s16x8*)&sm.c.comb[row >> 4][row & 15][64 + ch * 8];
        *(s16x8*)&qb[(size_t)(m0 + row) * 64 + ch * 8] = v;
    }
    {   // kfrag: wave task (kt = w&1, ks = w>>1)
        int kt = w & 1, ks2 = w >> 1;
        s16x8 v = *(const s16x8*)&sm.c.comb[kt][l15][ks2 * 32 + quad * 8];
        *(s16x8*)&kfrag[(size_t)(((b * 256 + t016 + kt) * 2 + ks2) * 64 + lane) * 8] = v;
    }
    {   // vfrag: wave task nt = w
        int nt = w;
        s16x8 v = *(const s16x8*)&sm.c.vsep[nt * 16 + l15][quad * 8];
        *(s16x8*)&vfrag[(size_t)(((b * 128 + kt32) * 4 + nt) * 64 + lane) * 8] = v;
    }
}

// ---------------------------------------------------------------------------
// Kernel 3: flash partials, S^T form, fixed m=0 softmax. Barrier-free per-wave
// K/V streaming; 32 queries per wave. K/V loads issued as asm volatile
// global_load_dwordx4 (unsinkable double-buffer), manual counted
// s_waitcnt vmcnt(8) + sched_barrier(0). Bias tile in LDS [32][269].
// S->P redistribution in-register via permlane swaps.
// Block = 4 waves = 4 batches. grid (128 g, 16 c) x 256.   [unchanged R18]
// ---------------------------------------------------------------------------
// RO = blds row offset (0 or 16), Q0S = first query of sub-strip, LS = l_sum
#define SOFT(N, AS, KL, RO, Q0S, LS, PLO, PHI) do {                           \
    f32x4 _vb = *(const f32x4*)&blds[(RO) + l15][(KL) + (N) * 16 + quad * 4]; \
    float _sv[4];                                                             \
    _Pragma("unroll")                                                         \
    for (int _r = 0; _r < 4; ++_r) {                                          \
        _sv[_r] = (AS)[_r] + _vb[_r];                                         \
        if (mask_on && (kabs + (N) * 16 + quad * 4 + _r > (Q0S) + l15))       \
            _sv[_r] = -__builtin_inff();                                      \
        float _p = __expf(_sv[_r]);                                           \
        _sv[_r] = _p;                                                         \
        LS += _p;                                                             \
    }                                                                         \
    PLO = pack2(_sv[0], _sv[1]);                                              \
    PHI = pack2(_sv[2], _sv[3]);                                              \
} while (0)

// In-register S->P(A-frag) redistribution (numerics proven R12-R18):
// (o0,o2)=pl16(pl32(p0,p2)), (o1,o3)=pl16(pl32(p1,p3)).
#define PERM4(P0, P1, P2, P3)                                                 \
    asm("v_permlane32_swap_b32 %0, %1" : "+v"(P0), "+v"(P2));                 \
    asm("v_permlane16_swap_b32 %0, %1" : "+v"(P0), "+v"(P2));                 \
    asm("v_permlane32_swap_b32 %0, %1" : "+v"(P1), "+v"(P3));                 \
    asm("v_permlane16_swap_b32 %0, %1" : "+v"(P1), "+v"(P3));

#define COMPUTEK(AK, BV, k0) do {                                             \
    int _kl = (k0) - kstart;                                                  \
    int kabs = (k0);                                                          \
    f32x4 _aS0 = (f32x4){0.f, 0.f, 0.f, 0.f};                                 \
    f32x4 _aS1 = (f32x4){0.f, 0.f, 0.f, 0.f};                                 \
    f32x4 _aS2 = (f32x4){0.f, 0.f, 0.f, 0.f};                                 \
    f32x4 _aS3 = (f32x4){0.f, 0.f, 0.f, 0.f};                                 \
    _aS0 = __builtin_amdgcn_mfma_f32_16x16x32_bf16(AK[0], aq0, _aS0, 0, 0, 0); \
    _aS0 = __builtin_amdgcn_mfma_f32_16x16x32_bf16(AK[1], aq1, _aS0, 0, 0, 0); \
    _aS1 = __builtin_amdgcn_mfma_f32_16x16x32_bf16(AK[2], aq0, _aS1, 0, 0, 0); \
    _aS1 = __builtin_amdgcn_mfma_f32_16x16x32_bf16(AK[3], aq1, _aS1, 0, 0, 0); \
    _aS2 = __builtin_amdgcn_mfma_f32_16x16x32_bf16(AK[0], aq2, _aS2, 0, 0, 0); \
    _aS2 = __builtin_amdgcn_mfma_f32_16x16x32_bf16(AK[1], aq3, _aS2, 0, 0, 0); \
    _aS3 = __builtin_amdgcn_mfma_f32_16x16x32_bf16(AK[2], aq2, _aS3, 0, 0, 0); \
    _aS3 = __builtin_amdgcn_mfma_f32_16x16x32_bf16(AK[3], aq3, _aS3, 0, 0, 0); \
    unsigned _p0, _p1, _p2, _p3, _p4, _p5, _p6, _p7;                          \
    SOFT(0, _aS0, _kl, 0, q0, l_sum0, _p0, _p1);                              \
    SOFT(1, _aS1, _kl, 0, q0, l_sum0, _p2, _p3);                              \
    SOFT(0, _aS2, _kl, 16, q0 + 16, l_sum1, _p4, _p5);                        \
    SOFT(1, _aS3, _kl, 16, q0 + 16, l_sum1, _p6, _p7);                        \
    PERM4(_p0, _p1, _p2, _p3);                                                \
    PERM4(_p4, _p5, _p6, _p7);                                                \
    u32x4 _apuA = (u32x4){_p0, _p1, _p2, _p3};                                \
    u32x4 _apuB = (u32x4){_p4, _p5, _p6, _p7};                                \
    s16x8 _apA = __builtin_bit_cast(s16x8, _apuA);                            \
    s16x8 _apB = __builtin_bit_cast(s16x8, _apuB);                            \
    _Pragma("unroll")                                                         \
    for (int _n = 0; _n < 4; ++_n) {                                          \
        accO[_n]     = __builtin_amdgcn_mfma_f32_16x16x32_bf16(_apA, BV[_n], accO[_n],     0, 0, 0); \
        accO[_n + 4] = __builtin_amdgcn_mfma_f32_16x16x32_bf16(_apB, BV[_n], accO[_n + 4], 0, 0, 0); \
    }                                                                         \
} while (0)

__global__ __launch_bounds__(256, 3) void flash_part(
    const short* __restrict__ qb, const short* __restrict__ kfrag,
    const short* __restrict__ vfrag, const float* __restrict__ bias,
    short* __restrict__ po)
{
    int g = blockIdx.x, c = blockIdx.y;
    if (c > (g >> 3)) return;                     // block-uniform early exit
    int q0 = g * 32;                              // first query of 32-strip
    int kstart = c * CK;
    int kend = min(kstart + CK, q0 + 32);         // wave-level key end

    __shared__ __align__(16) float blds[32][269]; // bias tile, stride 13 mod 32

    int w = threadIdx.x >> 6, lane = threadIdx.x & 63;  // w = batch
    int b = w;
    int l15 = lane & 15, quad = lane >> 4;

    // ---- stage bias: 8 passes, lanes along keys (1 KB contiguous/inst) ----
    #pragma unroll
    for (int p = 0; p < 8; ++p)
        *(f32x4*)&blds[p * 4 + w][lane * 4] =
            *(const f32x4*)&bias[(size_t)(q0 + p * 4 + w) * T_DIM + kstart + lane * 4];

    const short* qrow = qb + (size_t)(b * T_DIM + q0 + l15) * 64;
    s16x8 aq0 = *(const s16x8*)(qrow + quad * 8);
    s16x8 aq1 = *(const s16x8*)(qrow + 32 + quad * 8);
    const short* qrow2 = qrow + 16 * 64;
    s16x8 aq2 = *(const s16x8*)(qrow2 + quad * 8);
    s16x8 aq3 = *(const s16x8*)(qrow2 + 32 + quad * 8);

    float l_sum0 = 0.f, l_sum1 = 0.f;
    f32x4 accO[8];
    #pragma unroll
    for (int nt = 0; nt < 8; ++nt) accO[nt] = (f32x4){0.f, 0.f, 0.f, 0.f};

    const short* kfb = kfrag + (size_t)b * 256 * 2 * 512;
    const short* vfb = vfrag + (size_t)b * 128 * 4 * 512;
    bool mask_on = (kend > q0);                   // diagonal chunk only

    __syncthreads();                              // bias staged; vmem drained

    // ---- asm-pipelined barrier-free k-loop: 8 loads always in flight ----
    // step byte stride = 4 KB for both K and V (krel*128).
    const char* kadd = (const char*)kfb + (size_t)kstart * 128 + lane * 16;
    const char* vadd = (const char*)vfb + (size_t)kstart * 128 + lane * 16;
    s16x8 akA[4], akB[4], bvA[4], bvB[4];
    ALOAD4(akA[0], akA[1], akA[2], akA[3], kadd);
    ALOAD4(bvA[0], bvA[1], bvA[2], bvA[3], vadd);

    int nk = kend - kstart;
    int krel = 0;
    while (true) {
        bool more = (krel + 32 < nk);
        if (more) {
            const char* ka = kadd + (size_t)(krel + 32) * 128;
            const char* va = vadd + (size_t)(krel + 32) * 128;
            ALOAD4(akB[0], akB[1], akB[2], akB[3], ka);
            ALOAD4(bvB[0], bvB[1], bvB[2], bvB[3], va);
            WAITV8();                    // current step landed; next in flight
        } else {
            WAITV0();
        }
        COMPUTEK(akA, bvA, kstart + krel);
        if (!more) break;
        krel += 32;
        bool more2 = (krel + 32 < nk);
        if (more2) {
            const char* ka = kadd + (size_t)(krel + 32) * 128;
            const char* va = vadd + (size_t)(krel + 32) * 128;
            ALOAD4(akA[0], akA[1], akA[2], akA[3], ka);
            ALOAD4(bvA[0], bvA[1], bvA[2], bvA[3], va);
            WAITV8();
        } else {
            WAITV0();
        }
        COMPUTEK(akB, bvB, kstart + krel);
        if (!more2) break;
        krel += 32;
    }

    l_sum0 += __shfl_xor(l_sum0, 16, 64);
    l_sum0 += __shfl_xor(l_sum0, 32, 64);
    l_sum1 += __shfl_xor(l_sum1, 16, 64);
    l_sum1 += __shfl_xor(l_sum1, 32, 64);

    short* baseA = po + (size_t)((chunk_off(g * 2) + c) * 4 + b) * 1040;
    #pragma unroll
    for (int nt = 0; nt < 4; ++nt)
        #pragma unroll
        for (int r = 0; r < 4; ++r)
            baseA[(quad * 4 + r) * 64 + nt * 16 + l15] = f2bf(accO[nt][r]);
    if (quad == 0) baseA[1024 + l15] = f2bf(l_sum0);

    short* baseB = po + (size_t)((chunk_off(g * 2 + 1) + c) * 4 + b) * 1040;
    #pragma unroll
    for (int nt = 0; nt < 4; ++nt)
        #pragma unroll
        for (int r = 0; r < 4; ++r)
            baseB[(quad * 4 + r) * 64 + nt * 16 + l15] = f2bf(accO[nt + 4][r]);
    if (quad == 0) baseB[1024 + l15] = f2bf(l_sum1);
}

// ---------------------------------------------------------------------------
// Kernel 4: reduce partials + normalize. 512 x 256, 16B loads (8 thr/row).
// ---------------------------------------------------------------------------
__global__ __launch_bounds__(256) void flash_reduce(
    const short* __restrict__ po, float* __restrict__ out)
{
    int idx = blockIdx.x * 256 + threadIdx.x;     // 131072 = 16384 rows x 8
    int row = idx >> 3, c8 = idx & 7;
    int b = row >> 12, t = row & 4095;
    int qt = t >> 4, rloc = t & 15;
    int nc = (t >> 8) + 1;
    int off = chunk_off(qt);
    float o[8];
    #pragma unroll
    for (int j = 0; j < 8; ++j) o[j] = 0.f;
    float l = 0.f;
    #pragma unroll 1
    for (int cc = 0; cc < nc; ++cc) {
        const short* base = po + (size_t)((off + cc) * 4 + b) * 1040;
        s16x8 v = *(const s16x8*)&base[rloc * 64 + c8 * 8];
        #pragma unroll
        for (int j = 0; j < 8; ++j) o[j] += bf2f(v[j]);
        l += bf2f(base[1024 + rloc]);
    }
    float inv = 1.0f / l;
    f32x4 r0 = (f32x4){o[0] * inv, o[1] * inv, o[2] * inv, o[3] * inv};
    f32x4 r1 = (f32x4){o[4] * inv, o[5] * inv, o[6] * inv, o[7] * inv};
    float* op = &out[(size_t)row * 64 + c8 * 8];
    *(f32x4*)op = r0;
    *(f32x4*)(op + 4) = r1;
}

// ---------------------------------------------------------------------------
extern "C" void kernel_launch(void* const* d_in, const int* in_sizes, int n_in,
                              void* d_out, int out_size, void* d_ws, size_t ws_size,
                              hipStream_t stream) {
    (void)in_sizes; (void)n_in; (void)out_size; (void)ws_size;
    const float* x    = (const float*)d_in[0];
    const float* bias = (const float*)d_in[1];
    const float* wk   = (const float*)d_in[2];
    const float* wq   = (const float*)d_in[3];
    const float* wv   = (const float*)d_in[4];
    float* out = (float*)d_out;

    short* wfrag = (short*)d_ws;                       // 196608
    short* qb    = wfrag + 196608;                     // 1048576 each
    short* kfrag = qb + 1048576;
    short* vfrag = kfrag + 1048576;
    short* po    = vfrag + 1048576;                    // 2176*4*1040 = 9052160

    prep_frag<<<dim3(32, 3), dim3(256), 0, stream>>>(wk, wq, wv, wfrag);
    proj_fused<<<dim3(512), dim3(256), 0, stream>>>(x, wfrag, qb, kfrag, vfrag);
    flash_part<<<dim3(128, 16), dim3(256), 0, stream>>>(qb, kfrag, vfrag, bias, po);
    flash_reduce<<<dim3(512), dim3(256), 0, stream>>>(po, out);
}